// Round 11
// baseline (3862.115 us; speedup 1.0000x reference)
//
#include <hip/hip_runtime.h>
#include <cstdint>

#define B_ROWS 65536
#define D_IN   640
#define D_LAT  2560
#define K_SEL  32
#define NCAND  48
#define EPL    40   // 2560/64 elements per lane in wave topk
// np-exact K-panel boundaries (OpenBLAS SKYLAKEX Q=192): 192+192+128+128
#define P1 192
#define P2 384
#define P3 512

typedef __attribute__((ext_vector_type(8))) short short8;
typedef __attribute__((ext_vector_type(4))) float f32x4;

static __device__ __forceinline__ ushort f2bf(float f) {
    uint32_t u = __float_as_uint(f);
    u += 0x7fffu + ((u >> 16) & 1u);   // round-to-nearest-even
    return (ushort)(u >> 16);
}

// ---------------- generic fp32 -> bf16 convert (4 elems/thread) -------------------
__global__ __launch_bounds__(256) void cvt_bf16(const float* __restrict__ src,
                                                ushort* __restrict__ dst) {
    const size_t i = ((size_t)blockIdx.x * 256 + threadIdx.x) * 4;
    float4 v = *(const float4*)(src + i);
    ushort4 o;
    o.x = f2bf(v.x); o.y = f2bf(v.y); o.z = f2bf(v.z); o.w = f2bf(v.w);
    *(ushort4*)(dst + i) = o;
}

// ---------------- W_dec transpose: [640][2560] -> WdT [2560][640] ----------------
__global__ __launch_bounds__(256) void transpose_wdec(const float* __restrict__ Wd,
                                                      float* __restrict__ WdT) {
    __shared__ float t[32][33];
    const int j0 = blockIdx.x * 32;
    const int i0 = blockIdx.y * 32;
    const int tx = threadIdx.x & 31, ty = threadIdx.x >> 5;
#pragma unroll
    for (int q = 0; q < 4; ++q)
        t[ty + 8 * q][tx] = Wd[(size_t)(i0 + ty + 8 * q) * D_LAT + j0 + tx];
    __syncthreads();
#pragma unroll
    for (int q = 0; q < 4; ++q)
        WdT[(size_t)(j0 + ty + 8 * q) * D_IN + i0 + tx] = t[tx][ty + 8 * q];
}

// ---------------- bf16 MFMA filter GEMM (both operands pre-converted) ------------
// C[M][N] = A[M][K] x Wb[N][K]^T + bias. 128x128 tile, BK=32, 4 waves.
__global__ __launch_bounds__(256, 2) void enc_mfma(const ushort* __restrict__ A,
                                                   const ushort* __restrict__ Wb,
                                                   const float* __restrict__ bias,
                                                   float* __restrict__ C) {
    __shared__ ushort Al[128][40];   // pad 32->40 (80B row): 2-way conflicts = free
    __shared__ ushort Bl[128][40];
    const int tid = threadIdx.x;
    const int n0 = blockIdx.x * 128;
    const int m0 = blockIdx.y * 128;
    const int srow = tid >> 1, shalf = tid & 1;   // stager: row, 16-elem half
    const ushort* Ap = A  + (size_t)(m0 + srow) * D_IN + shalf * 16;
    const ushort* Bp = Wb + (size_t)(n0 + srow) * D_IN + shalf * 16;

    const int w = tid >> 6, l = tid & 63;
    const int wm = w >> 1, wn = w & 1;            // 2x2 waves over 128x128
    const int fr = l & 15, ko = l >> 4;           // frag row/col, k-octet

    f32x4 acc[4][4];
#pragma unroll
    for (int i = 0; i < 4; ++i)
#pragma unroll
        for (int j = 0; j < 4; ++j) acc[i][j] = (f32x4)0.0f;

    uint4 a0, a1, b0, b1;
#define LOADT(KT)                                                    \
    {                                                                \
        const uint* ap = (const uint*)(Ap + (KT) * 32);              \
        a0 = *(const uint4*)(ap);                                    \
        a1 = *(const uint4*)(ap + 4);                                \
        const uint* bp = (const uint*)(Bp + (KT) * 32);              \
        b0 = *(const uint4*)(bp);                                    \
        b1 = *(const uint4*)(bp + 4);                                \
    }

    LOADT(0);
    const int NT = D_IN / 32;   // 20
    for (int kt = 0; kt < NT; ++kt) {
        *(uint4*)&Al[srow][shalf * 16]     = a0;
        *(uint4*)&Al[srow][shalf * 16 + 8] = a1;
        *(uint4*)&Bl[srow][shalf * 16]     = b0;
        *(uint4*)&Bl[srow][shalf * 16 + 8] = b1;
        __syncthreads();
        if (kt + 1 < NT) LOADT(kt + 1);

        short8 af[4], bf[4];
#pragma unroll
        for (int fm = 0; fm < 4; ++fm)
            af[fm] = *(const short8*)&Al[wm * 64 + fm * 16 + fr][ko * 8];
#pragma unroll
        for (int fn = 0; fn < 4; ++fn)
            bf[fn] = *(const short8*)&Bl[wn * 64 + fn * 16 + fr][ko * 8];
#pragma unroll
        for (int fm = 0; fm < 4; ++fm)
#pragma unroll
            for (int fn = 0; fn < 4; ++fn)
                acc[fm][fn] = __builtin_amdgcn_mfma_f32_16x16x32_bf16(
                    af[fm], bf[fn], acc[fm][fn], 0, 0, 0);
        __syncthreads();
    }
#undef LOADT

#pragma unroll
    for (int fn = 0; fn < 4; ++fn) {
        const int col = n0 + wn * 64 + fn * 16 + fr;
        const float bb = bias[col];
#pragma unroll
        for (int fm = 0; fm < 4; ++fm) {
#pragma unroll
            for (int j = 0; j < 4; ++j) {
                const int row = m0 + wm * 64 + fm * 16 + ko * 4 + j;
                C[(size_t)row * D_LAT + col] = acc[fm][fn][j] + bb;
            }
        }
    }
}

// ---------------- Candidate top-NCAND per row (approx; set only matters) ---------
__global__ __launch_bounds__(256) void topk_cand(const float* __restrict__ lat,
                                                 int* __restrict__ cidx) {
    const int wv = threadIdx.x >> 6, lane = threadIdx.x & 63;
    const int r = blockIdx.x * 4 + wv;
    const float* row = lat + (size_t)r * D_LAT;

    float v[EPL];
#pragma unroll
    for (int e = 0; e < EPL; ++e) v[e] = row[e * 64 + lane];

    const float NEGINF = -__builtin_inff();
    uint64_t mask = 0;
    float lm = NEGINF; int li = 0x7fffffff;
#pragma unroll
    for (int e = 0; e < EPL; ++e)
        if (v[e] > lm) { lm = v[e]; li = e * 64 + lane; }

    for (int t = 0; t < NCAND; ++t) {
        float bv = lm; int bi = li;
#pragma unroll
        for (int off = 1; off < 64; off <<= 1) {
            float ov = __shfl_xor(bv, off);
            int   oi = __shfl_xor(bi, off);
            if (ov > bv || (ov == bv && oi < bi)) { bv = ov; bi = oi; }
        }
        if (lane == 0) cidx[(size_t)r * NCAND + t] = bi;
        if (li == bi) {
            mask |= 1ull << (bi >> 6);
            lm = NEGINF; li = 0x7fffffff;
#pragma unroll
            for (int e = 0; e < EPL; ++e)
                if (!((mask >> e) & 1) && v[e] > lm) { lm = v[e]; li = e * 64 + lane; }
        }
    }
}

// ---------------- Exact refine: np-bit-exact 4-panel chains, 4-way ILP -----------
// lane c recomputes candidate c's latent: 4 INDEPENDENT fp32 fmaf chains
// (k ascending within each panel), interleaved for ILP; combine ((a0+a1)+a2)+a3.
// Arithmetic per accumulator identical to the R9 passing kernel (bit-exact).
__global__ __launch_bounds__(256, 4) void refine_exact(const float* __restrict__ x,
                                                       const float* __restrict__ We,
                                                       const float* __restrict__ be,
                                                       const int* __restrict__ cidx,
                                                       float* __restrict__ sparse,
                                                       float* __restrict__ vals,
                                                       int* __restrict__ idxs) {
    const int tid = threadIdx.x;
    const int wv = tid >> 6, lane = tid & 63;
    const int r = blockIdx.x * 4 + wv;

    __shared__ float xs[4][D_IN];
    const float* xr = x + (size_t)r * D_IN;
#pragma unroll
    for (int q = 0; q < 10; ++q) xs[wv][lane + q * 64] = xr[lane + q * 64];

    const int j = (lane < NCAND) ? cidx[(size_t)r * NCAND + lane] : 0;
    const float4* wq4 = (const float4*)(We + (size_t)j * D_IN);
    const float4* xq4 = (const float4*)&xs[wv][0];

    float a0 = 0.f, a1 = 0.f, a2 = 0.f, a3 = 0.f;
    // quad indices: P0 = [0,48), P1 = [48,96), P2 = [96,128), P3 = [128,160)
#define FMA4(ACC, W, X)                                              \
    ACC = fmaf((W).x, (X).x, ACC); ACC = fmaf((W).y, (X).y, ACC);    \
    ACC = fmaf((W).z, (X).z, ACC); ACC = fmaf((W).w, (X).w, ACC);
#pragma unroll 4
    for (int q = 0; q < 32; ++q) {   // 4 streams live
        float4 w0 = wq4[q],        x0 = xq4[q];
        float4 w1 = wq4[48 + q],   x1 = xq4[48 + q];
        float4 w2 = wq4[96 + q],   x2 = xq4[96 + q];
        float4 w3 = wq4[128 + q],  x3 = xq4[128 + q];
        FMA4(a0, w0, x0)
        FMA4(a1, w1, x1)
        FMA4(a2, w2, x2)
        FMA4(a3, w3, x3)
    }
#pragma unroll 4
    for (int q = 32; q < 48; ++q) {  // P0/P1 tails
        float4 w0 = wq4[q],      x0 = xq4[q];
        float4 w1 = wq4[48 + q], x1 = xq4[48 + q];
        FMA4(a0, w0, x0)
        FMA4(a1, w1, x1)
    }
#undef FMA4
    const float val = (((a0 + a1) + a2) + a3) + be[j];

    const float NEGINF = -__builtin_inff();
    float mv = (lane < NCAND) ? val : NEGINF;
    int   mi = (lane < NCAND) ? j : 0x7fffffff;
    bool  selected = false;
    for (int t = 0; t < K_SEL; ++t) {
        float bv = mv; int bi = mi;
#pragma unroll
        for (int off = 1; off < 64; off <<= 1) {
            float ov = __shfl_xor(bv, off);
            int   oi = __shfl_xor(bi, off);
            if (ov > bv || (ov == bv && oi < bi)) { bv = ov; bi = oi; }
        }
        if (lane == 0) {
            vals[(size_t)r * K_SEL + t] = bv;
            idxs[(size_t)r * K_SEL + t] = bi;
        }
        if (bi == mi) {           // winner lane (candidate j's unique)
            selected = true;
            mv = NEGINF; mi = 0x7fffffff;
        }
    }

    // zero the block's 4 sparse rows, then scatter exact winners
    __syncthreads();
    float4 z; z.x = z.y = z.z = z.w = 0.f;
    float4* srow4 = (float4*)(sparse + (size_t)blockIdx.x * 4 * D_LAT);
    for (int p = tid; p < 4 * D_LAT / 4; p += 256) srow4[p] = z;
    __syncthreads();
    if (lane < NCAND && selected) sparse[(size_t)r * D_LAT + j] = val;
}

// ---------------- Decoder: recon[r] = sum_k vals[r][k] * WdT[idx[r][k]][:] + b_dec
__global__ __launch_bounds__(256) void dec_kernel(const float* __restrict__ vals,
                                                  const int* __restrict__ idxs,
                                                  const float* __restrict__ WdT,
                                                  const float* __restrict__ bdec,
                                                  float* __restrict__ recon) {
    const int wave = threadIdx.x >> 6, lane = threadIdx.x & 63;
    const int r = blockIdx.x * 4 + wave;

    float lv = 0.f; int li = 0;
    if (lane < K_SEL) {
        lv = vals[(size_t)r * K_SEL + lane];
        li = idxs[(size_t)r * K_SEL + lane];
    }
    float acc[10];
#pragma unroll
    for (int e = 0; e < 10; ++e) acc[e] = bdec[lane + e * 64];

#pragma unroll 4
    for (int k = 0; k < K_SEL; ++k) {
        float vkv = __shfl(lv, k);
        int   jj  = __shfl(li, k);
        const float* wr = WdT + (size_t)jj * D_IN + lane;
#pragma unroll
        for (int e = 0; e < 10; ++e) acc[e] = fmaf(vkv, wr[e * 64], acc[e]);
    }
    float* out = recon + (size_t)r * D_IN + lane;
#pragma unroll
    for (int e = 0; e < 10; ++e) out[e * 64] = acc[e];
}

extern "C" void kernel_launch(void* const* d_in, const int* in_sizes, int n_in,
                              void* d_out, int out_size, void* d_ws, size_t ws_size,
                              hipStream_t stream) {
    const float* x     = (const float*)d_in[0];
    const float* W_enc = (const float*)d_in[1];
    const float* b_enc = (const float*)d_in[2];
    const float* W_dec = (const float*)d_in[3];
    const float* b_dec = (const float*)d_in[4];

    float* recon  = (float*)d_out;                                  // [B][640]
    float* sparse = (float*)d_out + (size_t)B_ROWS * D_IN;          // [B][2560]

    // xB (bf16 copy of x, 84MB) parks in the recon region (167MB): recon is only
    // written by dec_kernel, which runs after enc_mfma has consumed xB.
    ushort* xB = (ushort*)recon;

    char* ws = (char*)d_ws;
    size_t off = 0;
    float*  WdT  = (float*) (ws + off); off += (size_t)D_LAT * D_IN * 4;    // 6.55 MB
    ushort* WeB  = (ushort*)(ws + off); off += (size_t)D_LAT * D_IN * 2;    // 3.28 MB
    int*    cidx = (int*)   (ws + off); off += (size_t)B_ROWS * NCAND * 4;  // 12.6 MB
    float*  vals = (float*) (ws + off); off += (size_t)B_ROWS * K_SEL * 4;  // 8.4 MB
    int*    idxs = (int*)   (ws + off);                                     // 8.4 MB

    hipLaunchKernelGGL(cvt_bf16, dim3((size_t)B_ROWS * D_IN / 1024), dim3(256), 0, stream,
                       x, xB);
    hipLaunchKernelGGL(cvt_bf16, dim3((size_t)D_LAT * D_IN / 1024), dim3(256), 0, stream,
                       W_enc, WeB);
    hipLaunchKernelGGL(transpose_wdec, dim3(D_LAT / 32, D_IN / 32), dim3(256), 0, stream,
                       W_dec, WdT);
    hipLaunchKernelGGL(enc_mfma, dim3(D_LAT / 128, B_ROWS / 128), dim3(256), 0, stream,
                       xB, WeB, b_enc, sparse);
    hipLaunchKernelGGL(topk_cand, dim3(B_ROWS / 4), dim3(256), 0, stream,
                       sparse, cidx);
    hipLaunchKernelGGL(refine_exact, dim3(B_ROWS / 4), dim3(256), 0, stream,
                       x, W_enc, b_enc, cidx, sparse, vals, idxs);
    hipLaunchKernelGGL(dec_kernel, dim3(B_ROWS / 4), dim3(256), 0, stream,
                       vals, idxs, WdT, b_dec, recon);
}

// Round 12
// 3132.462 us; speedup vs baseline: 1.2329x; 1.2329x over previous
//
#include <hip/hip_runtime.h>
#include <cstdint>

#define B_ROWS 65536
#define D_IN   640
#define D_LAT  2560
#define K_SEL  32
#define NCAND  48
#define EPL    40   // 2560/64 elements per lane in wave topk
// np-exact K-panel boundaries (OpenBLAS SKYLAKEX Q=192): 192+192+128+128
#define P1 192
#define P2 384
#define P3 512

typedef __attribute__((ext_vector_type(8))) short short8;
typedef __attribute__((ext_vector_type(4))) float f32x4;

static __device__ __forceinline__ ushort f2bf(float f) {
    uint32_t u = __float_as_uint(f);
    u += 0x7fffu + ((u >> 16) & 1u);   // round-to-nearest-even
    return (ushort)(u >> 16);
}

// ---------------- generic fp32 -> bf16 convert (4 elems/thread) -------------------
__global__ __launch_bounds__(256) void cvt_bf16(const float* __restrict__ src,
                                                ushort* __restrict__ dst) {
    const size_t i = ((size_t)blockIdx.x * 256 + threadIdx.x) * 4;
    float4 v = *(const float4*)(src + i);
    ushort4 o;
    o.x = f2bf(v.x); o.y = f2bf(v.y); o.z = f2bf(v.z); o.w = f2bf(v.w);
    *(ushort4*)(dst + i) = o;
}

// ---------------- W_dec transpose: [640][2560] -> WdT [2560][640] ----------------
__global__ __launch_bounds__(256) void transpose_wdec(const float* __restrict__ Wd,
                                                      float* __restrict__ WdT) {
    __shared__ float t[32][33];
    const int j0 = blockIdx.x * 32;
    const int i0 = blockIdx.y * 32;
    const int tx = threadIdx.x & 31, ty = threadIdx.x >> 5;
#pragma unroll
    for (int q = 0; q < 4; ++q)
        t[ty + 8 * q][tx] = Wd[(size_t)(i0 + ty + 8 * q) * D_LAT + j0 + tx];
    __syncthreads();
#pragma unroll
    for (int q = 0; q < 4; ++q)
        WdT[(size_t)(j0 + ty + 8 * q) * D_IN + i0 + tx] = t[tx][ty + 8 * q];
}

// ---------------- bf16 MFMA filter GEMM (both operands pre-converted) ------------
__global__ __launch_bounds__(256, 2) void enc_mfma(const ushort* __restrict__ A,
                                                   const ushort* __restrict__ Wb,
                                                   const float* __restrict__ bias,
                                                   float* __restrict__ C) {
    __shared__ ushort Al[128][40];   // pad 32->40 (80B row): 2-way conflicts = free
    __shared__ ushort Bl[128][40];
    const int tid = threadIdx.x;
    const int n0 = blockIdx.x * 128;
    const int m0 = blockIdx.y * 128;
    const int srow = tid >> 1, shalf = tid & 1;
    const ushort* Ap = A  + (size_t)(m0 + srow) * D_IN + shalf * 16;
    const ushort* Bp = Wb + (size_t)(n0 + srow) * D_IN + shalf * 16;

    const int w = tid >> 6, l = tid & 63;
    const int wm = w >> 1, wn = w & 1;
    const int fr = l & 15, ko = l >> 4;

    f32x4 acc[4][4];
#pragma unroll
    for (int i = 0; i < 4; ++i)
#pragma unroll
        for (int j = 0; j < 4; ++j) acc[i][j] = (f32x4)0.0f;

    uint4 a0, a1, b0, b1;
#define LOADT(KT)                                                    \
    {                                                                \
        const uint* ap = (const uint*)(Ap + (KT) * 32);              \
        a0 = *(const uint4*)(ap);                                    \
        a1 = *(const uint4*)(ap + 4);                                \
        const uint* bp = (const uint*)(Bp + (KT) * 32);              \
        b0 = *(const uint4*)(bp);                                    \
        b1 = *(const uint4*)(bp + 4);                                \
    }

    LOADT(0);
    const int NT = D_IN / 32;   // 20
    for (int kt = 0; kt < NT; ++kt) {
        *(uint4*)&Al[srow][shalf * 16]     = a0;
        *(uint4*)&Al[srow][shalf * 16 + 8] = a1;
        *(uint4*)&Bl[srow][shalf * 16]     = b0;
        *(uint4*)&Bl[srow][shalf * 16 + 8] = b1;
        __syncthreads();
        if (kt + 1 < NT) LOADT(kt + 1);

        short8 af[4], bf[4];
#pragma unroll
        for (int fm = 0; fm < 4; ++fm)
            af[fm] = *(const short8*)&Al[wm * 64 + fm * 16 + fr][ko * 8];
#pragma unroll
        for (int fn = 0; fn < 4; ++fn)
            bf[fn] = *(const short8*)&Bl[wn * 64 + fn * 16 + fr][ko * 8];
#pragma unroll
        for (int fm = 0; fm < 4; ++fm)
#pragma unroll
            for (int fn = 0; fn < 4; ++fn)
                acc[fm][fn] = __builtin_amdgcn_mfma_f32_16x16x32_bf16(
                    af[fm], bf[fn], acc[fm][fn], 0, 0, 0);
        __syncthreads();
    }
#undef LOADT

#pragma unroll
    for (int fn = 0; fn < 4; ++fn) {
        const int col = n0 + wn * 64 + fn * 16 + fr;
        const float bb = bias[col];
#pragma unroll
        for (int fm = 0; fm < 4; ++fm) {
#pragma unroll
            for (int j = 0; j < 4; ++j) {
                const int row = m0 + wm * 64 + fm * 16 + ko * 4 + j;
                C[(size_t)row * D_LAT + col] = acc[fm][fn][j] + bb;
            }
        }
    }
}

// ---------------- Candidate top-NCAND per row (approx; set only matters) ---------
__global__ __launch_bounds__(256) void topk_cand(const float* __restrict__ lat,
                                                 int* __restrict__ cidx) {
    const int wv = threadIdx.x >> 6, lane = threadIdx.x & 63;
    const int r = blockIdx.x * 4 + wv;
    const float* row = lat + (size_t)r * D_LAT;

    float v[EPL];
#pragma unroll
    for (int e = 0; e < EPL; ++e) v[e] = row[e * 64 + lane];

    const float NEGINF = -__builtin_inff();
    uint64_t mask = 0;
    float lm = NEGINF; int li = 0x7fffffff;
#pragma unroll
    for (int e = 0; e < EPL; ++e)
        if (v[e] > lm) { lm = v[e]; li = e * 64 + lane; }

    for (int t = 0; t < NCAND; ++t) {
        float bv = lm; int bi = li;
#pragma unroll
        for (int off = 1; off < 64; off <<= 1) {
            float ov = __shfl_xor(bv, off);
            int   oi = __shfl_xor(bi, off);
            if (ov > bv || (ov == bv && oi < bi)) { bv = ov; bi = oi; }
        }
        if (lane == 0) cidx[(size_t)r * NCAND + t] = bi;
        if (li == bi) {
            mask |= 1ull << (bi >> 6);
            lm = NEGINF; li = 0x7fffffff;
#pragma unroll
            for (int e = 0; e < EPL; ++e)
                if (!((mask >> e) & 1) && v[e] > lm) { lm = v[e]; li = e * 64 + lane; }
        }
    }
}

// ---------------- Exact refine: block-per-row, lane = (candidate, panel) ---------
// 192 lanes each run ONE panel chain (fp32 fmaf, k ascending) of its candidate;
// partials combined ((a0+a1)+a2)+a3 + bias in wave 0 -> bit-exact np values;
// top-32 with ties -> lower index. 4x shorter chains, 4x memory parallelism.
__global__ __launch_bounds__(256, 8) void refine_exact(const float* __restrict__ x,
                                                       const float* __restrict__ We,
                                                       const float* __restrict__ be,
                                                       const int* __restrict__ cidx,
                                                       float* __restrict__ sparse,
                                                       float* __restrict__ vals,
                                                       int* __restrict__ idxs) {
    const int tid = threadIdx.x;
    const int r = blockIdx.x;

    __shared__ float xs[D_IN];
    __shared__ float pv[NCAND][4];
    for (int i = tid; i < D_IN; i += 256) xs[i] = x[(size_t)r * D_IN + i];
    __syncthreads();

    if (tid < NCAND * 4) {
        const int c = tid >> 2, p = tid & 3;
        const int j = cidx[(size_t)r * NCAND + c];
        const float* wp = We + (size_t)j * D_IN;
        const int k0 = (p == 0) ? 0  : (p == 1) ? P1 : (p == 2) ? P2 : P3;
        const int k1 = (p == 0) ? P1 : (p == 1) ? P2 : (p == 2) ? P3 : D_IN;
        float a = 0.f;
#pragma unroll 4
        for (int k = k0; k < k1; k += 4) {
            const float4 wq = *(const float4*)(wp + k);
            const float4 xq = *(const float4*)&xs[k];
            a = fmaf(wq.x, xq.x, a);
            a = fmaf(wq.y, xq.y, a);
            a = fmaf(wq.z, xq.z, a);
            a = fmaf(wq.w, xq.w, a);
        }
        pv[c][p] = a;
    }
    __syncthreads();

    const int wv = tid >> 6, lane = tid & 63;
    if (wv == 0) {
        const float NEGINF = -__builtin_inff();
        float mv = NEGINF; int mi = 0x7fffffff;
        float val = 0.f; int j = 0;
        if (lane < NCAND) {
            j = cidx[(size_t)r * NCAND + lane];
            val = (((pv[lane][0] + pv[lane][1]) + pv[lane][2]) + pv[lane][3]) + be[j];
            mv = val; mi = j;
        }
        bool selected = false;
        for (int t = 0; t < K_SEL; ++t) {
            float bv = mv; int bi = mi;
#pragma unroll
            for (int off = 1; off < 64; off <<= 1) {
                float ov = __shfl_xor(bv, off);
                int   oi = __shfl_xor(bi, off);
                if (ov > bv || (ov == bv && oi < bi)) { bv = ov; bi = oi; }
            }
            if (lane == 0) {
                vals[(size_t)r * K_SEL + t] = bv;
                idxs[(size_t)r * K_SEL + t] = bi;
            }
            if (bi == mi) {       // winner lane (candidate indices unique)
                selected = true;
                mv = NEGINF; mi = 0x7fffffff;
            }
        }
        // stash winner info for scatter after the zero pass
        pv[0][0] = 0.f;  // (no-op keep-alive)
        if (lane < NCAND) {
            // reuse pv row 1..: store selection flags+vals for post-zero scatter
            ((int*)&pv[8][0])[lane]  = selected ? j : -1;
            ((float*)&pv[24][0])[lane] = val;
        }
    }
    __syncthreads();

    float4 z; z.x = z.y = z.z = z.w = 0.f;
    float4* srow4 = (float4*)(sparse + (size_t)r * D_LAT);
    for (int p = tid; p < D_LAT / 4; p += 256) srow4[p] = z;
    __syncthreads();
    if (tid < NCAND) {
        const int jj = ((int*)&pv[8][0])[tid];
        if (jj >= 0) sparse[(size_t)r * D_LAT + jj] = ((float*)&pv[24][0])[tid];
    }
}

// ---------------- Decoder: recon[r] = sum_k vals[r][k] * WdT[idx[r][k]][:] + b_dec
__global__ __launch_bounds__(256) void dec_kernel(const float* __restrict__ vals,
                                                  const int* __restrict__ idxs,
                                                  const float* __restrict__ WdT,
                                                  const float* __restrict__ bdec,
                                                  float* __restrict__ recon) {
    const int wave = threadIdx.x >> 6, lane = threadIdx.x & 63;
    const int r = blockIdx.x * 4 + wave;

    float lv = 0.f; int li = 0;
    if (lane < K_SEL) {
        lv = vals[(size_t)r * K_SEL + lane];
        li = idxs[(size_t)r * K_SEL + lane];
    }
    float acc[10];
#pragma unroll
    for (int e = 0; e < 10; ++e) acc[e] = bdec[lane + e * 64];

#pragma unroll 4
    for (int k = 0; k < K_SEL; ++k) {
        float vkv = __shfl(lv, k);
        int   jj  = __shfl(li, k);
        const float* wr = WdT + (size_t)jj * D_IN + lane;
#pragma unroll
        for (int e = 0; e < 10; ++e) acc[e] = fmaf(vkv, wr[e * 64], acc[e]);
    }
    float* out = recon + (size_t)r * D_IN + lane;
#pragma unroll
    for (int e = 0; e < 10; ++e) out[e * 64] = acc[e];
}

extern "C" void kernel_launch(void* const* d_in, const int* in_sizes, int n_in,
                              void* d_out, int out_size, void* d_ws, size_t ws_size,
                              hipStream_t stream) {
    const float* x     = (const float*)d_in[0];
    const float* W_enc = (const float*)d_in[1];
    const float* b_enc = (const float*)d_in[2];
    const float* W_dec = (const float*)d_in[3];
    const float* b_dec = (const float*)d_in[4];

    float* recon  = (float*)d_out;                                  // [B][640]
    float* sparse = (float*)d_out + (size_t)B_ROWS * D_IN;          // [B][2560]

    // xB (bf16 copy of x, 84MB) parks in the recon region (167MB): recon is only
    // written by dec_kernel, which runs after enc_mfma has consumed xB.
    ushort* xB = (ushort*)recon;

    char* ws = (char*)d_ws;
    size_t off = 0;
    float*  WdT  = (float*) (ws + off); off += (size_t)D_LAT * D_IN * 4;    // 6.55 MB
    ushort* WeB  = (ushort*)(ws + off); off += (size_t)D_LAT * D_IN * 2;    // 3.28 MB
    int*    cidx = (int*)   (ws + off); off += (size_t)B_ROWS * NCAND * 4;  // 12.6 MB
    float*  vals = (float*) (ws + off); off += (size_t)B_ROWS * K_SEL * 4;  // 8.4 MB
    int*    idxs = (int*)   (ws + off);                                     // 8.4 MB

    hipLaunchKernelGGL(cvt_bf16, dim3((size_t)B_ROWS * D_IN / 1024), dim3(256), 0, stream,
                       x, xB);
    hipLaunchKernelGGL(cvt_bf16, dim3((size_t)D_LAT * D_IN / 1024), dim3(256), 0, stream,
                       W_enc, WeB);
    hipLaunchKernelGGL(transpose_wdec, dim3(D_LAT / 32, D_IN / 32), dim3(256), 0, stream,
                       W_dec, WdT);
    hipLaunchKernelGGL(enc_mfma, dim3(D_LAT / 128, B_ROWS / 128), dim3(256), 0, stream,
                       xB, WeB, b_enc, sparse);
    hipLaunchKernelGGL(topk_cand, dim3(B_ROWS / 4), dim3(256), 0, stream,
                       sparse, cidx);
    hipLaunchKernelGGL(refine_exact, dim3(B_ROWS), dim3(256), 0, stream,
                       x, W_enc, b_enc, cidx, sparse, vals, idxs);
    hipLaunchKernelGGL(dec_kernel, dim3(B_ROWS / 4), dim3(256), 0, stream,
                       vals, idxs, WdT, b_dec, recon);
}

// Round 13
// 2195.256 us; speedup vs baseline: 1.7593x; 1.4269x over previous
//
#include <hip/hip_runtime.h>
#include <cstdint>

#define B_ROWS 65536
#define D_IN   640
#define D_LAT  2560
#define K_SEL  32
#define NCAND  48      // minimum candidates (threshold targets count in [48,64])
#define CCAP   64      // candidate capacity per row
// np-exact K-panel boundaries (OpenBLAS SKYLAKEX Q=192): 192+192+128+128
#define P1 192
#define P2 384
#define P3 512

typedef __attribute__((ext_vector_type(8))) short short8;
typedef __attribute__((ext_vector_type(4))) float f32x4;

static __device__ __forceinline__ ushort f2bf(float f) {
    uint32_t u = __float_as_uint(f);
    u += 0x7fffu + ((u >> 16) & 1u);   // round-to-nearest-even
    return (ushort)(u >> 16);
}

// ---------------- generic fp32 -> bf16 convert (4 elems/thread) -------------------
__global__ __launch_bounds__(256) void cvt_bf16(const float* __restrict__ src,
                                                ushort* __restrict__ dst) {
    const size_t i = ((size_t)blockIdx.x * 256 + threadIdx.x) * 4;
    float4 v = *(const float4*)(src + i);
    ushort4 o;
    o.x = f2bf(v.x); o.y = f2bf(v.y); o.z = f2bf(v.z); o.w = f2bf(v.w);
    *(ushort4*)(dst + i) = o;
}

// ---------------- W_dec transpose: [640][2560] -> WdT [2560][640] ----------------
__global__ __launch_bounds__(256) void transpose_wdec(const float* __restrict__ Wd,
                                                      float* __restrict__ WdT) {
    __shared__ float t[32][33];
    const int j0 = blockIdx.x * 32;
    const int i0 = blockIdx.y * 32;
    const int tx = threadIdx.x & 31, ty = threadIdx.x >> 5;
#pragma unroll
    for (int q = 0; q < 4; ++q)
        t[ty + 8 * q][tx] = Wd[(size_t)(i0 + ty + 8 * q) * D_LAT + j0 + tx];
    __syncthreads();
#pragma unroll
    for (int q = 0; q < 4; ++q)
        WdT[(size_t)(j0 + ty + 8 * q) * D_IN + i0 + tx] = t[tx][ty + 8 * q];
}

// ---------------- bf16 MFMA filter GEMM (both operands pre-converted) ------------
__global__ __launch_bounds__(256, 2) void enc_mfma(const ushort* __restrict__ A,
                                                   const ushort* __restrict__ Wb,
                                                   const float* __restrict__ bias,
                                                   float* __restrict__ C) {
    __shared__ ushort Al[128][40];   // pad 32->40 (80B row): 2-way conflicts = free
    __shared__ ushort Bl[128][40];
    const int tid = threadIdx.x;
    const int n0 = blockIdx.x * 128;
    const int m0 = blockIdx.y * 128;
    const int srow = tid >> 1, shalf = tid & 1;
    const ushort* Ap = A  + (size_t)(m0 + srow) * D_IN + shalf * 16;
    const ushort* Bp = Wb + (size_t)(n0 + srow) * D_IN + shalf * 16;

    const int w = tid >> 6, l = tid & 63;
    const int wm = w >> 1, wn = w & 1;
    const int fr = l & 15, ko = l >> 4;

    f32x4 acc[4][4];
#pragma unroll
    for (int i = 0; i < 4; ++i)
#pragma unroll
        for (int j = 0; j < 4; ++j) acc[i][j] = (f32x4)0.0f;

    uint4 a0, a1, b0, b1;
#define LOADT(KT)                                                    \
    {                                                                \
        const uint* ap = (const uint*)(Ap + (KT) * 32);              \
        a0 = *(const uint4*)(ap);                                    \
        a1 = *(const uint4*)(ap + 4);                                \
        const uint* bp = (const uint*)(Bp + (KT) * 32);              \
        b0 = *(const uint4*)(bp);                                    \
        b1 = *(const uint4*)(bp + 4);                                \
    }

    LOADT(0);
    const int NT = D_IN / 32;   // 20
    for (int kt = 0; kt < NT; ++kt) {
        *(uint4*)&Al[srow][shalf * 16]     = a0;
        *(uint4*)&Al[srow][shalf * 16 + 8] = a1;
        *(uint4*)&Bl[srow][shalf * 16]     = b0;
        *(uint4*)&Bl[srow][shalf * 16 + 8] = b1;
        __syncthreads();
        if (kt + 1 < NT) LOADT(kt + 1);

        short8 af[4], bf[4];
#pragma unroll
        for (int fm = 0; fm < 4; ++fm)
            af[fm] = *(const short8*)&Al[wm * 64 + fm * 16 + fr][ko * 8];
#pragma unroll
        for (int fn = 0; fn < 4; ++fn)
            bf[fn] = *(const short8*)&Bl[wn * 64 + fn * 16 + fr][ko * 8];
#pragma unroll
        for (int fm = 0; fm < 4; ++fm)
#pragma unroll
            for (int fn = 0; fn < 4; ++fn)
                acc[fm][fn] = __builtin_amdgcn_mfma_f32_16x16x32_bf16(
                    af[fm], bf[fn], acc[fm][fn], 0, 0, 0);
        __syncthreads();
    }
#undef LOADT

#pragma unroll
    for (int fn = 0; fn < 4; ++fn) {
        const int col = n0 + wn * 64 + fn * 16 + fr;
        const float bb = bias[col];
#pragma unroll
        for (int fm = 0; fm < 4; ++fm) {
#pragma unroll
            for (int j = 0; j < 4; ++j) {
                const int row = m0 + wm * 64 + fm * 16 + ko * 4 + j;
                C[(size_t)row * D_LAT + col] = acc[fm][fn][j] + bb;
            }
        }
    }
}

// ---------------- Candidate select by threshold (wave-per-row) -------------------
// Bisect count(>t) to land 48..64 candidates; ballot-compact their indices.
// Only the SET matters (must contain np's exact top-32); order/ties don't.
__global__ __launch_bounds__(256) void topk_cand(const float* __restrict__ lat,
                                                 int* __restrict__ cidx,
                                                 int* __restrict__ ccnt) {
    const int wv = threadIdx.x >> 6, lane = threadIdx.x & 63;
    const int r = blockIdx.x * 4 + wv;
    const float* row = lat + (size_t)r * D_LAT;

    float4 v[10];
#pragma unroll
    for (int e = 0; e < 10; ++e)
        v[e] = *(const float4*)(row + e * 256 + lane * 4);

    float mx = v[0].x;
#pragma unroll
    for (int e = 0; e < 10; ++e) {
        mx = fmaxf(mx, fmaxf(fmaxf(v[e].x, v[e].y), fmaxf(v[e].z, v[e].w)));
    }
#pragma unroll
    for (int off = 1; off < 64; off <<= 1) mx = fmaxf(mx, __shfl_xor(mx, off));

    auto countGt = [&](float t) -> int {
        int c = 0;
#pragma unroll
        for (int e = 0; e < 10; ++e)
            c += (v[e].x > t) + (v[e].y > t) + (v[e].z > t) + (v[e].w > t);
#pragma unroll
        for (int off = 1; off < 64; off <<= 1) c += __shfl_xor(c, off);
        return c;
    };

    float lo = mx - 2.0f;
    int clo = countGt(lo);
    if (clo < NCAND) { lo = mx - 4.0f; clo = countGt(lo); }
    if (clo < NCAND) { lo = mx - 16.0f; clo = countGt(lo); }   // paranoia tier
    float hi = mx;                                             // count(>mx)=0
    for (int it = 0; it < 28 && clo > CCAP; ++it) {
        const float mid = 0.5f * (lo + hi);
        const int c = countGt(mid);
        if (c >= NCAND) { lo = mid; clo = c; } else hi = mid;
    }

    int base = 0;
#pragma unroll
    for (int e = 0; e < 10; ++e) {
#pragma unroll
        for (int q = 0; q < 4; ++q) {
            const float val = (q == 0) ? v[e].x : (q == 1) ? v[e].y
                            : (q == 2) ? v[e].z : v[e].w;
            const bool take = val > lo;
            const uint64_t m = __ballot(take);
            const int pos = base + __popcll(m & ((1ull << lane) - 1ull));
            if (take && pos < CCAP)
                cidx[(size_t)r * CCAP + pos] = e * 256 + lane * 4 + q;
            base += __popcll(m);
        }
    }
    if (lane == 0) ccnt[r] = (base < CCAP) ? base : CCAP;
}

// ---------------- Exact refine: block-per-row, lane = (candidate, panel) ---------
// Up to 64 candidates; 4 panel chains each (fp32 fmaf, k ascending) -> LDS;
// wave 0 combines ((a0+a1)+a2)+a3 + bias (bit-exact np) and selects top-32,
// ties -> lower index.
__global__ __launch_bounds__(256, 8) void refine_exact(const float* __restrict__ x,
                                                       const float* __restrict__ We,
                                                       const float* __restrict__ be,
                                                       const int* __restrict__ cidx,
                                                       const int* __restrict__ ccnt,
                                                       float* __restrict__ sparse,
                                                       float* __restrict__ vals,
                                                       int* __restrict__ idxs) {
    const int tid = threadIdx.x;
    const int r = blockIdx.x;

    __shared__ float xs[D_IN];
    __shared__ float pv[CCAP][4];
    __shared__ int   selj[CCAP];
    __shared__ float selv[CCAP];
    const int cnt = ccnt[r];
    for (int i = tid; i < D_IN; i += 256) xs[i] = x[(size_t)r * D_IN + i];
    __syncthreads();

    const int c = tid >> 2, p = tid & 3;   // c in [0,64)
    if (c < cnt) {
        const int j = cidx[(size_t)r * CCAP + c];
        const float* wp = We + (size_t)j * D_IN;
        const int k0 = (p == 0) ? 0  : (p == 1) ? P1 : (p == 2) ? P2 : P3;
        const int k1 = (p == 0) ? P1 : (p == 1) ? P2 : (p == 2) ? P3 : D_IN;
        float a = 0.f;
#pragma unroll 4
        for (int k = k0; k < k1; k += 4) {
            const float4 wq = *(const float4*)(wp + k);
            const float4 xq = *(const float4*)&xs[k];
            a = fmaf(wq.x, xq.x, a);
            a = fmaf(wq.y, xq.y, a);
            a = fmaf(wq.z, xq.z, a);
            a = fmaf(wq.w, xq.w, a);
        }
        pv[c][p] = a;
    }
    __syncthreads();

    const int wv = tid >> 6, lane = tid & 63;
    if (wv == 0) {
        const float NEGINF = -__builtin_inff();
        float mv = NEGINF; int mi = 0x7fffffff;
        float val = 0.f; int j = 0;
        if (lane < cnt) {
            j = cidx[(size_t)r * CCAP + lane];
            val = (((pv[lane][0] + pv[lane][1]) + pv[lane][2]) + pv[lane][3]) + be[j];
            mv = val; mi = j;
        }
        bool selected = false;
        for (int t = 0; t < K_SEL; ++t) {
            float bv = mv; int bi = mi;
#pragma unroll
            for (int off = 1; off < 64; off <<= 1) {
                float ov = __shfl_xor(bv, off);
                int   oi = __shfl_xor(bi, off);
                if (ov > bv || (ov == bv && oi < bi)) { bv = ov; bi = oi; }
            }
            if (lane == 0) {
                vals[(size_t)r * K_SEL + t] = bv;
                idxs[(size_t)r * K_SEL + t] = bi;
            }
            if (bi == mi) {       // winner lane (candidate indices unique)
                selected = true;
                mv = NEGINF; mi = 0x7fffffff;
            }
        }
        selj[lane] = selected ? j : -1;
        selv[lane] = val;
    }
    __syncthreads();

    float4 z; z.x = z.y = z.z = z.w = 0.f;
    float4* srow4 = (float4*)(sparse + (size_t)r * D_LAT);
    for (int p2 = tid; p2 < D_LAT / 4; p2 += 256) srow4[p2] = z;
    __syncthreads();
    if (tid < CCAP) {
        const int jj = selj[tid];
        if (jj >= 0) sparse[(size_t)r * D_LAT + jj] = selv[tid];
    }
}

// ---------------- Decoder: recon[r] = sum_k vals[r][k] * WdT[idx[r][k]][:] + b_dec
__global__ __launch_bounds__(256) void dec_kernel(const float* __restrict__ vals,
                                                  const int* __restrict__ idxs,
                                                  const float* __restrict__ WdT,
                                                  const float* __restrict__ bdec,
                                                  float* __restrict__ recon) {
    const int wave = threadIdx.x >> 6, lane = threadIdx.x & 63;
    const int r = blockIdx.x * 4 + wave;

    float lv = 0.f; int li = 0;
    if (lane < K_SEL) {
        lv = vals[(size_t)r * K_SEL + lane];
        li = idxs[(size_t)r * K_SEL + lane];
    }
    float acc[10];
#pragma unroll
    for (int e = 0; e < 10; ++e) acc[e] = bdec[lane + e * 64];

#pragma unroll 4
    for (int k = 0; k < K_SEL; ++k) {
        float vkv = __shfl(lv, k);
        int   jj  = __shfl(li, k);
        const float* wr = WdT + (size_t)jj * D_IN + lane;
#pragma unroll
        for (int e = 0; e < 10; ++e) acc[e] = fmaf(vkv, wr[e * 64], acc[e]);
    }
    float* out = recon + (size_t)r * D_IN + lane;
#pragma unroll
    for (int e = 0; e < 10; ++e) out[e * 64] = acc[e];
}

extern "C" void kernel_launch(void* const* d_in, const int* in_sizes, int n_in,
                              void* d_out, int out_size, void* d_ws, size_t ws_size,
                              hipStream_t stream) {
    const float* x     = (const float*)d_in[0];
    const float* W_enc = (const float*)d_in[1];
    const float* b_enc = (const float*)d_in[2];
    const float* W_dec = (const float*)d_in[3];
    const float* b_dec = (const float*)d_in[4];

    float* recon  = (float*)d_out;                                  // [B][640]
    float* sparse = (float*)d_out + (size_t)B_ROWS * D_IN;          // [B][2560]

    // xB (bf16 copy of x, 84MB) parks in the recon region (167MB): recon is only
    // written by dec_kernel, which runs after enc_mfma has consumed xB.
    ushort* xB = (ushort*)recon;

    char* ws = (char*)d_ws;
    size_t off = 0;
    float*  WdT  = (float*) (ws + off); off += (size_t)D_LAT * D_IN * 4;    // 6.55 MB
    ushort* WeB  = (ushort*)(ws + off); off += (size_t)D_LAT * D_IN * 2;    // 3.28 MB
    int*    cidx = (int*)   (ws + off); off += (size_t)B_ROWS * CCAP * 4;   // 16.8 MB
    int*    ccnt = (int*)   (ws + off); off += (size_t)B_ROWS * 4;          // 0.26 MB
    float*  vals = (float*) (ws + off); off += (size_t)B_ROWS * K_SEL * 4;  // 8.4 MB
    int*    idxs = (int*)   (ws + off);                                     // 8.4 MB

    hipLaunchKernelGGL(cvt_bf16, dim3((size_t)B_ROWS * D_IN / 1024), dim3(256), 0, stream,
                       x, xB);
    hipLaunchKernelGGL(cvt_bf16, dim3((size_t)D_LAT * D_IN / 1024), dim3(256), 0, stream,
                       W_enc, WeB);
    hipLaunchKernelGGL(transpose_wdec, dim3(D_LAT / 32, D_IN / 32), dim3(256), 0, stream,
                       W_dec, WdT);
    hipLaunchKernelGGL(enc_mfma, dim3(D_LAT / 128, B_ROWS / 128), dim3(256), 0, stream,
                       xB, WeB, b_enc, sparse);
    hipLaunchKernelGGL(topk_cand, dim3(B_ROWS / 4), dim3(256), 0, stream,
                       sparse, cidx, ccnt);
    hipLaunchKernelGGL(refine_exact, dim3(B_ROWS), dim3(256), 0, stream,
                       x, W_enc, b_enc, cidx, ccnt, sparse, vals, idxs);
    hipLaunchKernelGGL(dec_kernel, dim3(B_ROWS / 4), dim3(256), 0, stream,
                       vals, idxs, WdT, b_dec, recon);
}

// Round 14
// 2187.625 us; speedup vs baseline: 1.7654x; 1.0035x over previous
//
#include <hip/hip_runtime.h>
#include <cstdint>

#define B_ROWS 65536
#define D_IN   640
#define D_LAT  2560
#define K_SEL  32
#define NCAND  48      // minimum candidates (threshold targets count in [48,64])
#define CCAP   64      // candidate capacity per row
// np-exact K-panel boundaries (OpenBLAS SKYLAKEX Q=192): 192+192+128+128
#define P1 192
#define P2 384
#define P3 512
#define XSTR 200       // padded panel stride in floats: banks 0,8,16,24

typedef __attribute__((ext_vector_type(8))) short short8;
typedef __attribute__((ext_vector_type(4))) float f32x4;

static __device__ __forceinline__ ushort f2bf(float f) {
    uint32_t u = __float_as_uint(f);
    u += 0x7fffu + ((u >> 16) & 1u);   // round-to-nearest-even
    return (ushort)(u >> 16);
}

// ---------------- generic fp32 -> bf16 convert (4 elems/thread) -------------------
__global__ __launch_bounds__(256) void cvt_bf16(const float* __restrict__ src,
                                                ushort* __restrict__ dst) {
    const size_t i = ((size_t)blockIdx.x * 256 + threadIdx.x) * 4;
    float4 v = *(const float4*)(src + i);
    ushort4 o;
    o.x = f2bf(v.x); o.y = f2bf(v.y); o.z = f2bf(v.z); o.w = f2bf(v.w);
    *(ushort4*)(dst + i) = o;
}

// ---------------- W_dec transpose: [640][2560] -> WdT [2560][640] ----------------
__global__ __launch_bounds__(256) void transpose_wdec(const float* __restrict__ Wd,
                                                      float* __restrict__ WdT) {
    __shared__ float t[32][33];
    const int j0 = blockIdx.x * 32;
    const int i0 = blockIdx.y * 32;
    const int tx = threadIdx.x & 31, ty = threadIdx.x >> 5;
#pragma unroll
    for (int q = 0; q < 4; ++q)
        t[ty + 8 * q][tx] = Wd[(size_t)(i0 + ty + 8 * q) * D_LAT + j0 + tx];
    __syncthreads();
#pragma unroll
    for (int q = 0; q < 4; ++q)
        WdT[(size_t)(j0 + ty + 8 * q) * D_IN + i0 + tx] = t[tx][ty + 8 * q];
}

// ---------------- bf16 MFMA filter GEMM (both operands pre-converted) ------------
__global__ __launch_bounds__(256, 2) void enc_mfma(const ushort* __restrict__ A,
                                                   const ushort* __restrict__ Wb,
                                                   const float* __restrict__ bias,
                                                   float* __restrict__ C) {
    __shared__ ushort Al[128][40];   // pad 32->40 (80B row): 2-way conflicts = free
    __shared__ ushort Bl[128][40];
    const int tid = threadIdx.x;
    const int n0 = blockIdx.x * 128;
    const int m0 = blockIdx.y * 128;
    const int srow = tid >> 1, shalf = tid & 1;
    const ushort* Ap = A  + (size_t)(m0 + srow) * D_IN + shalf * 16;
    const ushort* Bp = Wb + (size_t)(n0 + srow) * D_IN + shalf * 16;

    const int w = tid >> 6, l = tid & 63;
    const int wm = w >> 1, wn = w & 1;
    const int fr = l & 15, ko = l >> 4;

    f32x4 acc[4][4];
#pragma unroll
    for (int i = 0; i < 4; ++i)
#pragma unroll
        for (int j = 0; j < 4; ++j) acc[i][j] = (f32x4)0.0f;

    uint4 a0, a1, b0, b1;
#define LOADT(KT)                                                    \
    {                                                                \
        const uint* ap = (const uint*)(Ap + (KT) * 32);              \
        a0 = *(const uint4*)(ap);                                    \
        a1 = *(const uint4*)(ap + 4);                                \
        const uint* bp = (const uint*)(Bp + (KT) * 32);              \
        b0 = *(const uint4*)(bp);                                    \
        b1 = *(const uint4*)(bp + 4);                                \
    }

    LOADT(0);
    const int NT = D_IN / 32;   // 20
    for (int kt = 0; kt < NT; ++kt) {
        *(uint4*)&Al[srow][shalf * 16]     = a0;
        *(uint4*)&Al[srow][shalf * 16 + 8] = a1;
        *(uint4*)&Bl[srow][shalf * 16]     = b0;
        *(uint4*)&Bl[srow][shalf * 16 + 8] = b1;
        __syncthreads();
        if (kt + 1 < NT) LOADT(kt + 1);

        short8 af[4], bf[4];
#pragma unroll
        for (int fm = 0; fm < 4; ++fm)
            af[fm] = *(const short8*)&Al[wm * 64 + fm * 16 + fr][ko * 8];
#pragma unroll
        for (int fn = 0; fn < 4; ++fn)
            bf[fn] = *(const short8*)&Bl[wn * 64 + fn * 16 + fr][ko * 8];
#pragma unroll
        for (int fm = 0; fm < 4; ++fm)
#pragma unroll
            for (int fn = 0; fn < 4; ++fn)
                acc[fm][fn] = __builtin_amdgcn_mfma_f32_16x16x32_bf16(
                    af[fm], bf[fn], acc[fm][fn], 0, 0, 0);
        __syncthreads();
    }
#undef LOADT

#pragma unroll
    for (int fn = 0; fn < 4; ++fn) {
        const int col = n0 + wn * 64 + fn * 16 + fr;
        const float bb = bias[col];
#pragma unroll
        for (int fm = 0; fm < 4; ++fm) {
#pragma unroll
            for (int j = 0; j < 4; ++j) {
                const int row = m0 + wm * 64 + fm * 16 + ko * 4 + j;
                C[(size_t)row * D_LAT + col] = acc[fm][fn][j] + bb;
            }
        }
    }
}

// ---------------- Candidate select by threshold (wave-per-row) -------------------
__global__ __launch_bounds__(256) void topk_cand(const float* __restrict__ lat,
                                                 int* __restrict__ cidx,
                                                 int* __restrict__ ccnt) {
    const int wv = threadIdx.x >> 6, lane = threadIdx.x & 63;
    const int r = blockIdx.x * 4 + wv;
    const float* row = lat + (size_t)r * D_LAT;

    float4 v[10];
#pragma unroll
    for (int e = 0; e < 10; ++e)
        v[e] = *(const float4*)(row + e * 256 + lane * 4);

    float mx = v[0].x;
#pragma unroll
    for (int e = 0; e < 10; ++e) {
        mx = fmaxf(mx, fmaxf(fmaxf(v[e].x, v[e].y), fmaxf(v[e].z, v[e].w)));
    }
#pragma unroll
    for (int off = 1; off < 64; off <<= 1) mx = fmaxf(mx, __shfl_xor(mx, off));

    auto countGt = [&](float t) -> int {
        int c = 0;
#pragma unroll
        for (int e = 0; e < 10; ++e)
            c += (v[e].x > t) + (v[e].y > t) + (v[e].z > t) + (v[e].w > t);
#pragma unroll
        for (int off = 1; off < 64; off <<= 1) c += __shfl_xor(c, off);
        return c;
    };

    float lo = mx - 2.0f;
    int clo = countGt(lo);
    if (clo < NCAND) { lo = mx - 4.0f; clo = countGt(lo); }
    if (clo < NCAND) { lo = mx - 16.0f; clo = countGt(lo); }   // paranoia tier
    float hi = mx;                                             // count(>mx)=0
    for (int it = 0; it < 28 && clo > CCAP; ++it) {
        const float mid = 0.5f * (lo + hi);
        const int c = countGt(mid);
        if (c >= NCAND) { lo = mid; clo = c; } else hi = mid;
    }

    int base = 0;
#pragma unroll
    for (int e = 0; e < 10; ++e) {
#pragma unroll
        for (int q = 0; q < 4; ++q) {
            const float val = (q == 0) ? v[e].x : (q == 1) ? v[e].y
                            : (q == 2) ? v[e].z : v[e].w;
            const bool take = val > lo;
            const uint64_t m = __ballot(take);
            const int pos = base + __popcll(m & ((1ull << lane) - 1ull));
            if (take && pos < CCAP)
                cidx[(size_t)r * CCAP + pos] = e * 256 + lane * 4 + q;
            base += __popcll(m);
        }
    }
    if (lane == 0) ccnt[r] = (base < CCAP) ? base : CCAP;
}

// ---------------- Exact refine: block-per-row, lane = (candidate, panel) ---------
// 64B-line bursts (4 consecutive float4) kill the L1-thrash 4x L2 traffic;
// padded xs panels (stride 200: banks 0,8,16,24) kill the 4-way LDS conflict.
// Per-panel fp32 fmaf chain, k ascending; combine ((a0+a1)+a2)+a3 + bias ->
// bit-exact np values; top-32 ties -> lower index.
__global__ __launch_bounds__(256, 8) void refine_exact(const float* __restrict__ x,
                                                       const float* __restrict__ We,
                                                       const float* __restrict__ be,
                                                       const int* __restrict__ cidx,
                                                       const int* __restrict__ ccnt,
                                                       float* __restrict__ sparse,
                                                       float* __restrict__ vals,
                                                       int* __restrict__ idxs) {
    const int tid = threadIdx.x;
    const int r = blockIdx.x;

    __shared__ float xs[4 * XSTR];     // panel p at [p*XSTR, p*XSTR+len)
    __shared__ float pv[CCAP][4];
    __shared__ int   selj[CCAP];
    __shared__ float selv[CCAP];
    const int cnt = ccnt[r];
    for (int i = tid; i < D_IN; i += 256) {
        const float xv = x[(size_t)r * D_IN + i];
        const int p = (i >= P3) ? 3 : (i >= P2) ? 2 : (i >= P1) ? 1 : 0;
        const int k0 = (p == 0) ? 0 : (p == 1) ? P1 : (p == 2) ? P2 : P3;
        xs[p * XSTR + (i - k0)] = xv;
    }
    __syncthreads();

    const int c = tid >> 2, p = tid & 3;   // c in [0,64)
    if (c < cnt) {
        const int j = cidx[(size_t)r * CCAP + c];
        const int k0 = (p == 0) ? 0  : (p == 1) ? P1 : (p == 2) ? P2 : P3;
        const int k1 = (p == 0) ? P1 : (p == 1) ? P2 : (p == 2) ? P3 : D_IN;
        const float4* wp4 = (const float4*)(We + (size_t)j * D_IN + k0);
        const float4* xp4 = (const float4*)&xs[p * XSTR];
        const int nb = (k1 - k0) >> 4;     // 16-elem (64B) bursts: 12/12/8/8
        float a = 0.f;
#pragma unroll 2
        for (int b = 0; b < nb; ++b) {
            // one full 64B line of W per burst (MSHR-merged), + matching xs
            const float4 w0 = wp4[b * 4 + 0], w1 = wp4[b * 4 + 1];
            const float4 w2 = wp4[b * 4 + 2], w3 = wp4[b * 4 + 3];
            const float4 x0 = xp4[b * 4 + 0], x1 = xp4[b * 4 + 1];
            const float4 x2 = xp4[b * 4 + 2], x3 = xp4[b * 4 + 3];
            a = fmaf(w0.x, x0.x, a); a = fmaf(w0.y, x0.y, a);
            a = fmaf(w0.z, x0.z, a); a = fmaf(w0.w, x0.w, a);
            a = fmaf(w1.x, x1.x, a); a = fmaf(w1.y, x1.y, a);
            a = fmaf(w1.z, x1.z, a); a = fmaf(w1.w, x1.w, a);
            a = fmaf(w2.x, x2.x, a); a = fmaf(w2.y, x2.y, a);
            a = fmaf(w2.z, x2.z, a); a = fmaf(w2.w, x2.w, a);
            a = fmaf(w3.x, x3.x, a); a = fmaf(w3.y, x3.y, a);
            a = fmaf(w3.z, x3.z, a); a = fmaf(w3.w, x3.w, a);
        }
        pv[c][p] = a;
    }
    __syncthreads();

    const int wv = tid >> 6, lane = tid & 63;
    if (wv == 0) {
        const float NEGINF = -__builtin_inff();
        float mv = NEGINF; int mi = 0x7fffffff;
        float val = 0.f; int j = 0;
        if (lane < cnt) {
            j = cidx[(size_t)r * CCAP + lane];
            val = (((pv[lane][0] + pv[lane][1]) + pv[lane][2]) + pv[lane][3]) + be[j];
            mv = val; mi = j;
        }
        bool selected = false;
        for (int t = 0; t < K_SEL; ++t) {
            float bv = mv; int bi = mi;
#pragma unroll
            for (int off = 1; off < 64; off <<= 1) {
                float ov = __shfl_xor(bv, off);
                int   oi = __shfl_xor(bi, off);
                if (ov > bv || (ov == bv && oi < bi)) { bv = ov; bi = oi; }
            }
            if (lane == 0) {
                vals[(size_t)r * K_SEL + t] = bv;
                idxs[(size_t)r * K_SEL + t] = bi;
            }
            if (bi == mi) {       // winner lane (candidate indices unique)
                selected = true;
                mv = NEGINF; mi = 0x7fffffff;
            }
        }
        selj[lane] = selected ? j : -1;
        selv[lane] = val;
    }
    __syncthreads();

    float4 z; z.x = z.y = z.z = z.w = 0.f;
    float4* srow4 = (float4*)(sparse + (size_t)r * D_LAT);
    for (int p2 = tid; p2 < D_LAT / 4; p2 += 256) srow4[p2] = z;
    __syncthreads();
    if (tid < CCAP) {
        const int jj = selj[tid];
        if (jj >= 0) sparse[(size_t)r * D_LAT + jj] = selv[tid];
    }
}

// ---------------- Decoder: recon[r] = sum_k vals[r][k] * WdT[idx[r][k]][:] + b_dec
__global__ __launch_bounds__(256) void dec_kernel(const float* __restrict__ vals,
                                                  const int* __restrict__ idxs,
                                                  const float* __restrict__ WdT,
                                                  const float* __restrict__ bdec,
                                                  float* __restrict__ recon) {
    const int wave = threadIdx.x >> 6, lane = threadIdx.x & 63;
    const int r = blockIdx.x * 4 + wave;

    float lv = 0.f; int li = 0;
    if (lane < K_SEL) {
        lv = vals[(size_t)r * K_SEL + lane];
        li = idxs[(size_t)r * K_SEL + lane];
    }
    float acc[10];
#pragma unroll
    for (int e = 0; e < 10; ++e) acc[e] = bdec[lane + e * 64];

#pragma unroll 4
    for (int k = 0; k < K_SEL; ++k) {
        float vkv = __shfl(lv, k);
        int   jj  = __shfl(li, k);
        const float* wr = WdT + (size_t)jj * D_IN + lane;
#pragma unroll
        for (int e = 0; e < 10; ++e) acc[e] = fmaf(vkv, wr[e * 64], acc[e]);
    }
    float* out = recon + (size_t)r * D_IN + lane;
#pragma unroll
    for (int e = 0; e < 10; ++e) out[e * 64] = acc[e];
}

extern "C" void kernel_launch(void* const* d_in, const int* in_sizes, int n_in,
                              void* d_out, int out_size, void* d_ws, size_t ws_size,
                              hipStream_t stream) {
    const float* x     = (const float*)d_in[0];
    const float* W_enc = (const float*)d_in[1];
    const float* b_enc = (const float*)d_in[2];
    const float* W_dec = (const float*)d_in[3];
    const float* b_dec = (const float*)d_in[4];

    float* recon  = (float*)d_out;                                  // [B][640]
    float* sparse = (float*)d_out + (size_t)B_ROWS * D_IN;          // [B][2560]

    // xB (bf16 copy of x, 84MB) parks in the recon region (167MB): recon is only
    // written by dec_kernel, which runs after enc_mfma has consumed xB.
    ushort* xB = (ushort*)recon;

    char* ws = (char*)d_ws;
    size_t off = 0;
    float*  WdT  = (float*) (ws + off); off += (size_t)D_LAT * D_IN * 4;    // 6.55 MB
    ushort* WeB  = (ushort*)(ws + off); off += (size_t)D_LAT * D_IN * 2;    // 3.28 MB
    int*    cidx = (int*)   (ws + off); off += (size_t)B_ROWS * CCAP * 4;   // 16.8 MB
    int*    ccnt = (int*)   (ws + off); off += (size_t)B_ROWS * 4;          // 0.26 MB
    float*  vals = (float*) (ws + off); off += (size_t)B_ROWS * K_SEL * 4;  // 8.4 MB
    int*    idxs = (int*)   (ws + off);                                     // 8.4 MB

    hipLaunchKernelGGL(cvt_bf16, dim3((size_t)B_ROWS * D_IN / 1024), dim3(256), 0, stream,
                       x, xB);
    hipLaunchKernelGGL(cvt_bf16, dim3((size_t)D_LAT * D_IN / 1024), dim3(256), 0, stream,
                       W_enc, WeB);
    hipLaunchKernelGGL(transpose_wdec, dim3(D_LAT / 32, D_IN / 32), dim3(256), 0, stream,
                       W_dec, WdT);
    hipLaunchKernelGGL(enc_mfma, dim3(D_LAT / 128, B_ROWS / 128), dim3(256), 0, stream,
                       xB, WeB, b_enc, sparse);
    hipLaunchKernelGGL(topk_cand, dim3(B_ROWS / 4), dim3(256), 0, stream,
                       sparse, cidx, ccnt);
    hipLaunchKernelGGL(refine_exact, dim3(B_ROWS), dim3(256), 0, stream,
                       x, W_enc, b_enc, cidx, ccnt, sparse, vals, idxs);
    hipLaunchKernelGGL(dec_kernel, dim3(B_ROWS / 4), dim3(256), 0, stream,
                       vals, idxs, WdT, b_dec, recon);
}